// Round 19
// baseline (28.814 us; speedup 1.0000x reference)
//
#include <hip/hip_runtime.h>

// 2D Gaussian splatting renderer, MI355X. R21.
// N=4096 gaussians, 512x512x3 fp32 image, 64 tiles of 64x64 px.
//
// R21 theory: R20 = 28.50us (best). Decomposition: fixed ~6.6 + pre ~2.5-3
// + blend ~11-12 (issue floor ~9) + merge ~0.7; residual ~5us = stall +
// imbalance (imbalance fixes proven net-negative, R13-R17). Remaining
// mechanism: blend's serial ds_read->compute dependency. LDS broadcast
// read latency ~120cyc; at 4 waves/SIMD, if the compiler doesn't pipeline
// across iterations the latency is partially exposed (~matches the gap).
// Fix, bit-exact: explicit 1-iter register prefetch of sA/sB/sC[k+1]
// before computing iter k (+ #pragma unroll 2). Values/FP order unchanged.
// Predict 28.5 -> 26.5-27.5 if latency was exposed; neutral if compiler
// already pipelined (then structure is at its practical floor).

#define N_G    4096
#define W_IMG  512
#define TL_    64
#define NTILES 64
#define MAXG   1024
#define LOG2E  1.44269504088896340736f

typedef float v2f __attribute__((ext_vector_type(2)));

struct PreScratch {
    float dep[MAXG];
    unsigned short srv[MAXG];
};

__global__ __launch_bounds__(512, 4)
void gs_fused(const float* __restrict__ pos2d,
              const float* __restrict__ cov2d,
              const float* __restrict__ opacity,
              const float* __restrict__ color,
              float* __restrict__ out) {
    __shared__ __align__(16) float4 sA[MAXG];     // px, py, qa, qb (depth order)
    __shared__ __align__(16) float4 sB[MAXG];     // qc, lb, cr, cg
    __shared__ __align__(8)  float2 sC[MAXG];     // cb, inv2qa
    __shared__ int s_wcnt[8];
    __shared__ union {
        PreScratch pre;                           // pre-blend scratch
        __align__(16) float4 m[2][512];           // post-blend merge buffers
    } su;

    const int id = blockIdx.x;
    const int sub  = id >> 6;              // 0..7 -> (x-quadrant, y-half)
    const int tile = ((id & 63) * 21 + sub * 11) & 63;
    const int tx = tile >> 3;
    const int ty = tile & 7;
    const float left = (float)(tx * TL_);
    const float top  = (float)(ty * TL_);
    const int t = threadIdx.x;
    const int wave = t >> 6;               // 0..7
    const int lane = t & 63;

    // ===== phase 1: radius + bbox cull over all 4096 (8 gaussians/thread)
    unsigned int bits = 0;
    int wcnt = 0;
    float dep8[8];
    #pragma unroll
    for (int it = 0; it < 8; ++it) {
        const int g = wave * 512 + it * 64 + lane;
        const float px = pos2d[g * 3 + 0];
        const float py = pos2d[g * 3 + 1];
        dep8[it] = pos2d[g * 3 + 2];
        const float4 cv = ((const float4*)cov2d)[g];
        const float trace = cv.x + cv.w;
        const float det = cv.x * cv.w - cv.y * cv.z;
        const float tmp = trace * trace - 4.0f * det;
        const float term2 = 0.5f * sqrtf(fmaxf(tmp, 0.0f));
        const float radius = 3.0f * sqrtf(fmaxf(0.5f * trace - term2, 0.5f * trace + term2));
        const bool m = (px + radius >= left) && (px - radius < left + (float)TL_) &&
                       (py + radius >= top)  && (py - radius < top  + (float)TL_);
        bits |= (m ? 1u : 0u) << it;
        wcnt += __popcll(__ballot(m));
    }
    if (lane == 0) s_wcnt[wave] = wcnt;
    __syncthreads();
    int total = 0, base = 0;
    #pragma unroll
    for (int w = 0; w < 8; ++w) {
        const int c = s_wcnt[w];
        total += c;
        if (w < wave) base += c;
    }
    const int totalc = min(total, MAXG);   // never hit: max measured ~640

    // ===== phase 2: cross-wave-stable compact (ascending original index)
    #pragma unroll
    for (int it = 0; it < 8; ++it) {
        const bool m = (bits >> it) & 1u;
        const unsigned long long bal = __ballot(m);
        const int prefix = __popcll(bal & ((1ULL << lane) - 1ULL));
        const int pos = base + prefix;
        if (m && pos < MAXG) {
            su.pre.srv[pos] = (unsigned short)(wave * 512 + it * 64 + lane);
            su.pre.dep[pos] = dep8[it];
        }
        base += __popcll(bal);
    }
    if (t < 8) {                           // sentinel pad for float4 rank loop
        const int p = totalc + t;
        if (p < MAXG) su.pre.dep[p] = 1e30f;
    }
    __syncthreads();

    // ===== phase 3: rank by (depth, slot) + derive coefficients
    if (t < totalc) {
        const float dt = su.pre.dep[t];
        const float4* d4 = (const float4*)su.pre.dep;
        int rank = 0;
        const int n4 = (totalc + 3) >> 2;
        for (int j4 = 0; j4 < n4; ++j4) {
            const float4 d = d4[j4];
            const int j = 4 * j4;
            rank += (d.x < dt) || (d.x == dt && (j + 0) < t);
            rank += (d.y < dt) || (d.y == dt && (j + 1) < t);
            rank += (d.z < dt) || (d.z == dt && (j + 2) < t);
            rank += (d.w < dt) || (d.w == dt && (j + 3) < t);
        }
        const int g = su.pre.srv[t];
        const float px = pos2d[g * 3 + 0];
        const float py = pos2d[g * 3 + 1];
        const float a = cov2d[g * 4 + 0];
        const float b = cov2d[g * 4 + 1];
        const float c = cov2d[g * 4 + 2];
        const float d = cov2d[g * 4 + 3];
        const float det = a * d - b * c;
        const float inv_det = 1.0f / det;
        const float ia  = d * inv_det;
        const float ibc = (-b * inv_det) + (-c * inv_det);  // ref's ib+ic rounding
        const float idd = a * inv_det;
        const float op = opacity[g];
        const float cr = fmaxf(color[g * 3 + 0] + 0.5f, 0.0f);
        const float cg = fmaxf(color[g * 3 + 1] + 0.5f, 0.0f);
        const float cb = fmaxf(color[g * 3 + 2] + 0.5f, 0.0f);
        const float qa = -0.5f * ia * LOG2E;                // < 0 (cov PD)
        sA[rank] = make_float4(px, py, qa, -0.5f * ibc * LOG2E);
        sB[rank] = make_float4(-0.5f * idd * LOG2E, __log2f(op), cr, cg);
        sC[rank] = make_float2(cb, 1.0f / (2.0f * qa));     // inv2qa (finite)
    }
    __syncthreads();

    // ===== phase 4: blend with bit-exact far-field fast path + 1-iter
    //       register prefetch of the wave-uniform LDS reads
    const int s0 = (wave * totalc) >> 3;
    const int s1 = ((wave + 1) * totalc) >> 3;

    // 16x32 patch: lane = (y row within half, x strip)
    const int xq = sub & 3;                // X quadrant (16 px)
    const int yh = sub >> 2;               // Y half (32 px)
    const int X0 = tx * TL_ + xq * 16 + (lane & 1) * 8;   // per-lane
    const int Y  = ty * TL_ + yh * 32 + (lane >> 1);
    const float fY = (float)Y;
    const float fXs = (float)X0;

    const v2f fX0 = {(float)(X0 + 0), (float)(X0 + 1)};
    const v2f fX1 = {(float)(X0 + 2), (float)(X0 + 3)};
    const v2f fX2 = {(float)(X0 + 4), (float)(X0 + 5)};
    const v2f fX3 = {(float)(X0 + 6), (float)(X0 + 7)};

    v2f R0 = {0.f, 0.f}, R1 = R0, R2 = R0, R3 = R0;
    v2f G0 = R0, G1 = R0, G2 = R0, G3 = R0;
    v2f B0 = R0, B1 = R0, B2 = R0, B3 = R0;
    v2f T0 = {1.f, 1.f}, T1 = T0, T2 = T0, T3 = T0;

    // prologue: load first entry
    float4 A  = sA[s0];
    float4 Bv = sB[s0];
    float2 Cv = sC[s0];

    #pragma unroll 2
    for (int k = s0; k < s1; ++k) {
        // prefetch next entry (unconditional; clamp keeps index in-bounds,
        // garbage value is never used when k+1 == s1)
        const int kn = min(k + 1, MAXG - 1);
        const float4 An  = sA[kn];
        const float4 Bn  = sB[kn];
        const float2 Cn  = sC[kn];

        const float dy   = fY - A.y;
        const float qbdy = A.w * dy;
        const float bse  = Bv.x * dy * dy + Bv.y;      // qc*dy^2 + lb

        // far test: concave q(dx); max over [dx0s, dx0s+7] = q(clamp(vertex))
        const float dx0s = fXs - A.x;
        const float dxv  = -qbdy * Cv.y;               // vertex = -qbdy/(2qa)
        const float dxc  = __builtin_amdgcn_fmed3f(dxv, dx0s, dx0s + 7.0f);
        const float qmax = (A.z * dxc + qbdy) * dxc + bse;

        if (!__any(qmax > -6.65f)) {
            // all 64 lanes x 8 px: e < 0.01 guaranteed -> alpha == 0.01
            // exactly (med3 would return the literal). Bit-identical ops.
            const v2f al = {0.01f, 0.01f};
            const v2f cr2 = {Bv.z, Bv.z};
            const v2f cg2 = {Bv.w, Bv.w};
            const v2f cb2 = {Cv.x, Cv.x};
#define PX_FAST(Tp, Rp, Gp, Bp)                                               \
            {                                                                 \
                const v2f w_ = al * Tp;                                       \
                Rp = __builtin_elementwise_fma(w_, cr2, Rp);                  \
                Gp = __builtin_elementwise_fma(w_, cg2, Gp);                  \
                Bp = __builtin_elementwise_fma(w_, cb2, Bp);                  \
                Tp = Tp - w_;                                                 \
            }
            PX_FAST(T0, R0, G0, B0)
            PX_FAST(T1, R1, G1, B1)
            PX_FAST(T2, R2, G2, B2)
            PX_FAST(T3, R3, G3, B3)
#undef PX_FAST
        } else {
            const v2f az2 = {A.z, A.z};
            const v2f ax2 = {A.x, A.x};
            const v2f qb2 = {qbdy, qbdy};
            const v2f bs2 = {bse, bse};
            const v2f lo2 = {0.01f, 0.01f};
            const v2f hi2 = {0.99f, 0.99f};
            const v2f cr2 = {Bv.z, Bv.z};
            const v2f cg2 = {Bv.w, Bv.w};
            const v2f cb2 = {Cv.x, Cv.x};
#define PX_PAIR(FXP, Tp, Rp, Gp, Bp)                                          \
            {                                                                 \
                const v2f dx = FXP - ax2;                                     \
                v2f q = __builtin_elementwise_fma(az2, dx, qb2);              \
                q = __builtin_elementwise_fma(q, dx, bs2);                    \
                v2f e;                                                        \
                e.x = exp2f(q.x); e.y = exp2f(q.y);                           \
                v2f al;                                                       \
                al.x = __builtin_amdgcn_fmed3f(e.x, lo2.x, hi2.x);            \
                al.y = __builtin_amdgcn_fmed3f(e.y, lo2.y, hi2.y);            \
                const v2f w_ = al * Tp;                                       \
                Rp = __builtin_elementwise_fma(w_, cr2, Rp);                  \
                Gp = __builtin_elementwise_fma(w_, cg2, Gp);                  \
                Bp = __builtin_elementwise_fma(w_, cb2, Bp);                  \
                Tp = Tp - w_;                                                 \
            }
            PX_PAIR(fX0, T0, R0, G0, B0)
            PX_PAIR(fX1, T1, R1, G1, B1)
            PX_PAIR(fX2, T2, R2, G2, B2)
            PX_PAIR(fX3, T3, R3, G3, B3)
#undef PX_PAIR
        }

        A = An; Bv = Bn; Cv = Cn;
    }

    // ===== phase 5: tree merge with 2 buffers
#define PUBLISH(buf)                                                          \
    {                                                                         \
        (buf)[0 * 64 + lane] = make_float4(R0.x, G0.x, B0.x, T0.x);           \
        (buf)[1 * 64 + lane] = make_float4(R0.y, G0.y, B0.y, T0.y);           \
        (buf)[2 * 64 + lane] = make_float4(R1.x, G1.x, B1.x, T1.x);           \
        (buf)[3 * 64 + lane] = make_float4(R1.y, G1.y, B1.y, T1.y);           \
        (buf)[4 * 64 + lane] = make_float4(R2.x, G2.x, B2.x, T2.x);           \
        (buf)[5 * 64 + lane] = make_float4(R2.y, G2.y, B2.y, T2.y);           \
        (buf)[6 * 64 + lane] = make_float4(R3.x, G3.x, B3.x, T3.x);           \
        (buf)[7 * 64 + lane] = make_float4(R3.y, G3.y, B3.y, T3.y);           \
    }
#define COMPOSE(buf)                                                          \
    {                                                                         \
        _Pragma("unroll")                                                     \
        for (int j = 0; j < 4; ++j) {                                         \
            const float4 m0 = (buf)[(2 * j + 0) * 64 + lane];                 \
            const float4 m1 = (buf)[(2 * j + 1) * 64 + lane];                 \
            const v2f mr = {m0.x, m1.x};                                      \
            const v2f mg = {m0.y, m1.y};                                      \
            const v2f mb = {m0.z, m1.z};                                      \
            const v2f mt = {m0.w, m1.w};                                      \
            v2f* Rj = j == 0 ? &R0 : j == 1 ? &R1 : j == 2 ? &R2 : &R3;       \
            v2f* Gj = j == 0 ? &G0 : j == 1 ? &G1 : j == 2 ? &G2 : &G3;       \
            v2f* Bj = j == 0 ? &B0 : j == 1 ? &B1 : j == 2 ? &B2 : &B3;       \
            v2f* Tj = j == 0 ? &T0 : j == 1 ? &T1 : j == 2 ? &T2 : &T3;       \
            *Rj = __builtin_elementwise_fma(*Tj, mr, *Rj);                    \
            *Gj = __builtin_elementwise_fma(*Tj, mg, *Gj);                    \
            *Bj = __builtin_elementwise_fma(*Tj, mb, *Bj);                    \
            *Tj = *Tj * mt;                                                   \
        }                                                                     \
    }

    // round 1a: (0,1) and (2,3)
    if (wave == 1) PUBLISH(su.m[0]);
    if (wave == 3) PUBLISH(su.m[1]);
    __syncthreads();
    if (wave == 0) COMPOSE(su.m[0]);
    if (wave == 2) COMPOSE(su.m[1]);
    __syncthreads();
    // round 1b: (4,5) and (6,7)
    if (wave == 5) PUBLISH(su.m[0]);
    if (wave == 7) PUBLISH(su.m[1]);
    __syncthreads();
    if (wave == 4) COMPOSE(su.m[0]);
    if (wave == 6) COMPOSE(su.m[1]);
    __syncthreads();
    // round 2: (0,2) and (4,6)
    if (wave == 2) PUBLISH(su.m[0]);
    if (wave == 6) PUBLISH(su.m[1]);
    __syncthreads();
    if (wave == 0) COMPOSE(su.m[0]);
    if (wave == 4) COMPOSE(su.m[1]);
    __syncthreads();
    // round 3: (0,4)
    if (wave == 4) PUBLISH(su.m[0]);
    __syncthreads();
    if (wave == 0) {
        COMPOSE(su.m[0]);
#define OUT_PX(i, rv, gv, bv)                                                 \
        {                                                                     \
            const int o = ((X0 + (i)) * W_IMG + Y) * 3;                       \
            out[o + 0] = rv;                                                  \
            out[o + 1] = gv;                                                  \
            out[o + 2] = bv;                                                  \
        }
        OUT_PX(0, R0.x, G0.x, B0.x)
        OUT_PX(1, R0.y, G0.y, B0.y)
        OUT_PX(2, R1.x, G1.x, B1.x)
        OUT_PX(3, R1.y, G1.y, B1.y)
        OUT_PX(4, R2.x, G2.x, B2.x)
        OUT_PX(5, R2.y, G2.y, B2.y)
        OUT_PX(6, R3.x, G3.x, B3.x)
        OUT_PX(7, R3.y, G3.y, B3.y)
#undef OUT_PX
    }
#undef PUBLISH
#undef COMPOSE
}

extern "C" void kernel_launch(void* const* d_in, const int* in_sizes, int n_in,
                              void* d_out, int out_size, void* d_ws, size_t ws_size,
                              hipStream_t stream) {
    const float* pos2d   = (const float*)d_in[0];
    const float* cov2d   = (const float*)d_in[1];
    const float* opacity = (const float*)d_in[2];
    const float* color   = (const float*)d_in[3];
    float* out = (float*)d_out;

    gs_fused<<<NTILES * 8, 512, 0, stream>>>(pos2d, cov2d, opacity, color, out);
}